// Round 3
// baseline (144.200 us; speedup 1.0000x reference)
//
#include <hip/hip_runtime.h>

#define NT 2048
#define ND 512
#define NH 128
#define NKW 7
#define KP 960
#define NTOK 16384

typedef float f32x4 __attribute__((ext_vector_type(4)));
typedef __bf16 bf16x8 __attribute__((ext_vector_type(8)));
typedef unsigned short u16;
typedef unsigned int u32;
typedef u16 u16x8 __attribute__((ext_vector_type(8)));

__device__ __forceinline__ u16 f2bf(float f){
  u32 u = __builtin_bit_cast(u32, f);
  return (u16)((u + 0x7fffu + ((u>>16)&1u)) >> 16);
}
__device__ __forceinline__ float bf2f(u16 s){
  u32 u = ((u32)s)<<16;
  return __builtin_bit_cast(float, u);
}
__device__ __forceinline__ bf16x8 pack8(const float4& a, const float4& b){
  u16x8 u;
  u[0]=f2bf(a.x); u[1]=f2bf(a.y); u[2]=f2bf(a.z); u[3]=f2bf(a.w);
  u[4]=f2bf(b.x); u[5]=f2bf(b.y); u[6]=f2bf(b.z); u[7]=f2bf(b.w);
  return __builtin_bit_cast(bf16x8, u);
}
__device__ __forceinline__ void store16_lds(void* p, const u16 u[8]){
  u32 d0 = (u32)u[0] | ((u32)u[1]<<16);
  u32 d1 = (u32)u[2] | ((u32)u[3]<<16);
  u32 d2 = (u32)u[4] | ((u32)u[5]<<16);
  u32 d3 = (u32)u[6] | ((u32)u[7]<<16);
  int4 vv; vv.x=(int)d0; vv.y=(int)d1; vv.z=(int)d2; vv.w=(int)d3;
  *(int4*)p = vv;
}

// ---------------- prep: coalesced transposes via LDS tile
__global__ __launch_bounds__(256) void prep_kernel(
    const float* __restrict__ W1, const float* __restrict__ W2,
    const float* __restrict__ b2, u16* __restrict__ W1T, u16* __restrict__ B2T)
{
  __shared__ float T[64][65];
  const int b = blockIdx.x, tid = threadIdx.x;
  if (b < 16){
    const int d0 = (b>>1)*64, h0 = (b&1)*64;
    #pragma unroll
    for (int r=0;r<16;++r){
      int idx=r*256+tid; int dl=idx>>6, hl=idx&63;
      T[dl][hl] = W1[(size_t)(d0+dl)*NH + h0+hl];
    }
    __syncthreads();
    #pragma unroll
    for (int r=0;r<16;++r){
      int idx=r*256+tid; int hl=idx>>6, dl=idx&63;
      W1T[(size_t)(h0+hl)*ND + d0+dl] = f2bf(T[dl][hl]);
    }
  } else if (b < 128){
    const int bb = b-16;
    const int h0 = (bb&1)*64, c0 = (bb>>1)*64;
    #pragma unroll
    for (int r=0;r<16;++r){
      int idx=r*256+tid; int hl=idx>>6, cl=idx&63;
      T[hl][cl] = W2[(size_t)(h0+hl)*(NKW*ND) + c0+cl];
    }
    __syncthreads();
    #pragma unroll
    for (int r=0;r<16;++r){
      int idx=r*256+tid; int cl=idx>>6, hl=idx&63;
      int c = c0+cl; int n = c & (ND-1), k = c >> 9;
      B2T[(size_t)n*KP + k*NH + h0+hl] = f2bf(T[hl][cl]);
    }
  } else {
    const int bb = b-128;
    #pragma unroll
    for (int r=0;r<16;++r){
      int idx = bb*4096 + r*256 + tid;
      int n = idx>>6, j = idx&63;
      B2T[(size_t)n*KP + 896 + j] = (j<NKW)? f2bf(b2[(size_t)j*ND+n]) : (u16)0;
    }
  }
}

// ---------------- fused: rowsum + gemm1(h) + gemm2(conv) + residual/LN/relu
// BM=64 rows/block, 512 threads (8 waves), grid 256
__global__ __launch_bounds__(512,2) void fused_kernel(
    const float* __restrict__ x, const u16* __restrict__ W1T,
    const float* __restrict__ b1, const u16* __restrict__ B2T,
    const float* __restrict__ gamma, const float* __restrict__ beta,
    float* __restrict__ out)
{
  __shared__ __align__(16) u16 xb_lds[64*512];   // 64KB x-tile bf16, swizzled rows of 1KB
  __shared__ __align__(16) u16 h_lds[64*128];    // 16KB h, swizzled rows of 256B
  __shared__ __align__(16) u16 At[2][64*64];     // 16KB A' double buffer
  __shared__ float rs_lds[70];
  __shared__ float s_lds[64][8];
  __shared__ float red_s[64][8], red_q[64][8];
  __shared__ float mu_lds[64], rstd_lds[64];

  const int tid = threadIdx.x, w = tid>>6, l = tid&63;
  const int m_base = blockIdx.x*64;

  // ---- phase 1: x-tile -> LDS bf16 + rowsums (incl. 6 halo rows)
  {
    const int r = tid>>3, slot = tid&7;           // 64 rows x 8 slots
    const float4* p = (const float4*)(x + (size_t)(m_base+r)*ND + slot*64);
    float s = 0.f;
    #pragma unroll
    for (int i=0;i<8;++i){
      float4 a = p[2*i], b2v = p[2*i+1];
      s += (a.x+a.y)+(a.z+a.w) + (b2v.x+b2v.y)+(b2v.z+b2v.w);
      u16 u[8] = {f2bf(a.x),f2bf(a.y),f2bf(a.z),f2bf(a.w),
                  f2bf(b2v.x),f2bf(b2v.y),f2bf(b2v.z),f2bf(b2v.w)};
      int byte = r*1024 + ((slot*128 + i*16) ^ ((r&7)<<4));
      store16_lds((char*)xb_lds + byte, u);
    }
    s += __shfl_xor(s,1); s += __shfl_xor(s,2); s += __shfl_xor(s,4);
    if (slot==0) rs_lds[3+r] = s;
    // halo rows j in {0,1,2,67,68,69}: one per wave (waves 0..5), lanes 0..7
    if (l < 8 && w < 6){
      int j = (w<3)? w : w+64;
      int tg2 = m_base + j - 3;
      float s2 = 0.f;
      if (tg2 >= 0 && tg2 < NTOK){
        const float4* p2 = (const float4*)(x + (size_t)tg2*ND + l*64);
        #pragma unroll
        for (int i=0;i<16;++i){ float4 v = p2[i]; s2 += (v.x+v.y)+(v.z+v.w); }
      }
      s2 += __shfl_xor(s2,1); s2 += __shfl_xor(s2,2); s2 += __shfl_xor(s2,4);
      if (l==0) rs_lds[j] = s2;
    }
  }
  __syncthreads();
  // window sums s[t,k]
  {
    int rr = tid>>3, k = tid&7;
    float v = 0.f;
    if (k < NKW){
      int ti = (m_base+rr) & (NT-1);
      int idx = ti + k - 3;
      if (idx >= 0 && idx < NT) v = rs_lds[rr+k];
    }
    s_lds[rr][k] = v;
  }

  // ---- phase 2: gemm1: h = relu(x @ W1 + b1) -> h_lds
  {
    const int wm = w>>2, wn = w&3;                 // 2M x 4N waves, tile 32x32
    f32x4 acc1[2][2] = {};
    const u16* bbase = W1T + (size_t)(wn*32 + (l&15))*ND + (l>>4)*8;
    #pragma unroll
    for (int kc=0;kc<16;++kc){
      bf16x8 af[2], bfr[2];
      #pragma unroll
      for (int mi=0;mi<2;++mi){
        int rr = wm*32 + mi*16 + (l&15);
        int byte = rr*1024 + ((kc*64 + (l>>4)*16) ^ ((rr&7)<<4));
        af[mi] = *(const bf16x8*)((const char*)xb_lds + byte);
      }
      #pragma unroll
      for (int ni=0;ni<2;++ni)
        bfr[ni] = *(const bf16x8*)(bbase + (size_t)ni*16*ND + kc*32);
      #pragma unroll
      for (int mi=0;mi<2;++mi)
        #pragma unroll
        for (int ni=0;ni<2;++ni)
          acc1[mi][ni] = __builtin_amdgcn_mfma_f32_16x16x32_bf16(af[mi], bfr[ni], acc1[mi][ni],0,0,0);
    }
    #pragma unroll
    for (int ni=0;ni<2;++ni){
      int col = wn*32 + ni*16 + (l&15);
      float bias = b1[col];
      #pragma unroll
      for (int mi=0;mi<2;++mi){
        #pragma unroll
        for (int r=0;r<4;++r){
          int row = wm*32 + mi*16 + (l>>4)*4 + r;
          float v = fmaxf(acc1[mi][ni][r] + bias, 0.f);
          int byte = row*256 + ((2*col) ^ ((row&7)<<4));
          *(u16*)((char*)h_lds + byte) = f2bf(v);
        }
      }
    }
  }
  __syncthreads();

  // ---- phase 3: gemm2: A'(s*h | s) @ B2T, K'=960 (15 chunks of 64)
  f32x4 acc[4][4] = {};
  bf16x8 bufA[2][4], bufB[2][4];
  const int row = tid>>3, slot = tid&7;

  auto loadB = [&](int kc, bf16x8 (*bf)[4]){
    #pragma unroll
    for (int kk=0;kk<2;++kk)
      #pragma unroll
      for (int ni=0;ni<4;++ni){
        int rowB = w*64 + ni*16 + (l&15);
        bf[kk][ni] = *(const bf16x8*)((const char*)B2T + (size_t)rowB*(KP*2) + kc*128 + kk*64 + (l>>4)*16);
      }
  };
  auto stageA = [&](u16* dst, int kc2){
    u16 u[8];
    if (kc2 < 14){
      float sv = s_lds[row][kc2>>1];
      const char* src = (const char*)h_lds + row*256 + (((kc2&1)*128 + slot*16) ^ ((row&7)<<4));
      u16x8 hv = *(const u16x8*)src;
      #pragma unroll
      for (int j=0;j<8;++j) u[j] = f2bf(bf2f(hv[j])*sv);
    } else {
      #pragma unroll
      for (int j=0;j<8;++j){
        int e2 = slot*8+j;
        u[j] = (e2<NKW)? f2bf(s_lds[row][e2]) : (u16)0;
      }
    }
    int byte = row*128 + ((slot*16) ^ ((row&7)<<4));
    store16_lds((char*)dst + byte, u);
  };

  loadB(0, bufA);
  stageA(At[0], 0);
  __syncthreads();

  #pragma unroll
  for (int kc=0;kc<15;++kc){
    bf16x8 (*bc)[4] = (kc&1)? bufB : bufA;
    bf16x8 (*bn)[4] = (kc&1)? bufA : bufB;
    if (kc<14){
      loadB(kc+1, bn);
      __builtin_amdgcn_sched_barrier(0);   // pin prefetch issue before MFMAs
    }
    const char* curA = (const char*)At[kc&1];
    #pragma unroll
    for (int kk=0;kk<2;++kk){
      bf16x8 af[4];
      #pragma unroll
      for (int mi=0;mi<4;++mi){
        int r2 = mi*16 + (l&15);
        int byte = r2*128 + (((kk*64)+((l>>4)*16)) ^ ((r2&7)<<4));
        af[mi] = *(const bf16x8*)(curA + byte);
      }
      #pragma unroll
      for (int mi=0;mi<4;++mi)
        #pragma unroll
        for (int ni=0;ni<4;++ni)
          acc[mi][ni] = __builtin_amdgcn_mfma_f32_16x16x32_bf16(af[mi], bc[kk][ni], acc[mi][ni],0,0,0);
    }
    if (kc<14){
      stageA(At[(kc&1)^1], kc+1);
      __syncthreads();
    }
  }

  // ---- phase 4: residual + LN + relu
  #pragma unroll
  for (int mi=0;mi<4;++mi){
    #pragma unroll
    for (int r=0;r<4;++r){
      int m = mi*16 + (l>>4)*4 + r;
      int tg = m_base + m;
      float ps=0.f, pq=0.f;
      #pragma unroll
      for (int ni=0;ni<4;++ni){
        int n = w*64 + ni*16 + (l&15);
        float v = acc[mi][ni][r] + x[(size_t)tg*ND + n];
        acc[mi][ni][r] = v;
        ps += v; pq += v*v;
      }
      #pragma unroll
      for (int msk=1; msk<16; msk<<=1){ ps += __shfl_xor(ps,msk); pq += __shfl_xor(pq,msk); }
      if ((l&15)==0){ red_s[m][w]=ps; red_q[m][w]=pq; }
    }
  }
  __syncthreads();
  if (tid < 64){
    float ssum=0.f, sq=0.f;
    #pragma unroll
    for (int ww=0; ww<8; ++ww){ ssum += red_s[tid][ww]; sq += red_q[tid][ww]; }
    float mu = ssum * (1.0f/ND);
    float var = sq*(1.0f/ND) - mu*mu;
    mu_lds[tid] = mu;
    rstd_lds[tid] = rsqrtf(var + 1e-3f);
  }
  __syncthreads();
  float gv[4], bv[4];
  #pragma unroll
  for (int ni=0;ni<4;++ni){
    int n = w*64 + ni*16 + (l&15);
    gv[ni] = gamma[n]; bv[ni] = beta[n];
  }
  #pragma unroll
  for (int mi=0;mi<4;++mi){
    #pragma unroll
    for (int r=0;r<4;++r){
      int m = mi*16 + (l>>4)*4 + r;
      int tg = m_base + m;
      float mu = mu_lds[m], rstd = rstd_lds[m];
      #pragma unroll
      for (int ni=0;ni<4;++ni){
        int n = w*64 + ni*16 + (l&15);
        float v = (acc[mi][ni][r]-mu)*rstd*gv[ni] + bv[ni];
        out[(size_t)tg*ND + n] = fmaxf(v, 0.f);
      }
    }
  }
}

extern "C" void kernel_launch(void* const* d_in, const int* in_sizes, int n_in,
                              void* d_out, int out_size, void* d_ws, size_t ws_size,
                              hipStream_t stream)
{
  (void)in_sizes; (void)n_in; (void)out_size; (void)ws_size;
  const float* x     = (const float*)d_in[0];
  const float* W1    = (const float*)d_in[1];
  const float* b1    = (const float*)d_in[2];
  const float* W2    = (const float*)d_in[3];
  const float* b2    = (const float*)d_in[4];
  const float* gamma = (const float*)d_in[5];
  const float* beta  = (const float*)d_in[6];
  float* out = (float*)d_out;

  char* ws = (char*)d_ws;
  u16* W1T = (u16*)(ws);               // 131072 B
  u16* B2T = (u16*)(ws + 131072);      // 983040 B

  prep_kernel<<<136, 256, 0, stream>>>(W1, W2, b2, W1T, B2T);
  fused_kernel<<<256, 512, 0, stream>>>(x, W1T, b1, B2T, gamma, beta, out);
}

// Round 4
// 139.599 us; speedup vs baseline: 1.0330x; 1.0330x over previous
//
#include <hip/hip_runtime.h>

#define NT 2048
#define ND 512
#define NH 128
#define NKW 7
#define NTOK 16384

typedef float f32x4 __attribute__((ext_vector_type(4)));
typedef __bf16 bf16x8 __attribute__((ext_vector_type(8)));
typedef unsigned short u16;
typedef unsigned int u32;
typedef u16 u16x8 __attribute__((ext_vector_type(8)));

__device__ __forceinline__ u16 f2bf(float f){
  u32 u = __builtin_bit_cast(u32, f);
  return (u16)((u + 0x7fffu + ((u>>16)&1u)) >> 16);
}
__device__ __forceinline__ float bf2f(u16 s){
  u32 u = ((u32)s)<<16;
  return __builtin_bit_cast(float, u);
}
__device__ __forceinline__ bf16x8 pack8(const float4& a, const float4& b){
  u16x8 u;
  u[0]=f2bf(a.x); u[1]=f2bf(a.y); u[2]=f2bf(a.z); u[3]=f2bf(a.w);
  u[4]=f2bf(b.x); u[5]=f2bf(b.y); u[6]=f2bf(b.z); u[7]=f2bf(b.w);
  return __builtin_bit_cast(bf16x8, u);
}
__device__ __forceinline__ void store16(void* p, const u16 u[8]){
  u32 d0 = (u32)u[0] | ((u32)u[1]<<16);
  u32 d1 = (u32)u[2] | ((u32)u[3]<<16);
  u32 d2 = (u32)u[4] | ((u32)u[5]<<16);
  u32 d3 = (u32)u[6] | ((u32)u[7]<<16);
  int4 vv; vv.x=(int)d0; vv.y=(int)d1; vv.z=(int)d2; vv.w=(int)d3;
  *(int4*)p = vv;
}

// ---------------- prep2: fragment-linear weight layouts
// W1F: frag f (0..8191): n=f&127, sk=f>>7 -> elements W1[sk*8+j][n]
// B3:  frag g (0..61439): n=g&511, sc=g>>9 (kappa_base=sc*8)
//      kb<896: kwin=kb>>7,h=kb&127 -> W2[h+j][kwin*512+n]; else bias rows b2[jj*512+n]
__global__ __launch_bounds__(256) void prep2_kernel(
    const float* __restrict__ W1, const float* __restrict__ W2,
    const float* __restrict__ b2, u16* __restrict__ W1F, u16* __restrict__ B3)
{
  int f = blockIdx.x*256 + threadIdx.x;
  u16 u[8];
  if (f < 8192){
    int n = f & 127, sk = f >> 7, kb = sk*8;
    #pragma unroll
    for (int j=0;j<8;++j) u[j] = f2bf(W1[(size_t)(kb+j)*NH + n]);
    store16(W1F + (size_t)f*8, u);
  } else {
    int g = f - 8192;
    int n = g & 511, sc = g >> 9, kb = sc*8;
    if (kb < 896){
      int kwin = kb >> 7, h = kb & 127;
      #pragma unroll
      for (int j=0;j<8;++j) u[j] = f2bf(W2[(size_t)(h+j)*(NKW*ND) + kwin*ND + n]);
    } else {
      int jb = kb - 896;
      #pragma unroll
      for (int j=0;j<8;++j){ int jj = jb+j; u[j] = (jj<NKW)? f2bf(b2[(size_t)jj*ND + n]) : (u16)0; }
    }
    store16(B3 + (size_t)g*8, u);
  }
}

// ---------------- fused: rowsum + gemm1 + gemm2 + residual/LN/relu
// BM=64, 512 threads (8 waves), grid 256
__global__ __launch_bounds__(512,2) void fused_kernel(
    const float* __restrict__ x, const u16* __restrict__ W1F,
    const float* __restrict__ b1, const u16* __restrict__ B3,
    const float* __restrict__ gamma, const float* __restrict__ beta,
    float* __restrict__ out)
{
  __shared__ __align__(16) u16 h_lds[2*64*64];       // 16KB: [half][row][64], swizzled
  __shared__ __align__(16) u16 At0[64*64], At1[64*64]; // 8KB each
  __shared__ float rs_lds[70];
  __shared__ float s_lds[64][8];
  __shared__ float red_s[64][8], red_q[64][8];
  __shared__ float mu_lds[64], rstd_lds[64];

  const int tid = threadIdx.x, w = tid>>6, l = tid&63;
  const int m_base = blockIdx.x*64;

  // ---- P1: row sums (fully coalesced per-row reads) + halo rows
  #pragma unroll
  for (int r=0;r<8;++r){
    int row = w*8 + r;
    const float4* pr = (const float4*)(x + (size_t)(m_base+row)*ND + l*8);
    float4 a = pr[0], b = pr[1];
    float s = (a.x+a.y)+(a.z+a.w)+((b.x+b.y)+(b.z+b.w));
    s += __shfl_xor(s,1); s += __shfl_xor(s,2); s += __shfl_xor(s,4);
    s += __shfl_xor(s,8); s += __shfl_xor(s,16); s += __shfl_xor(s,32);
    if (l==0) rs_lds[3+row] = s;
  }
  if (w < 6){
    int j = (w<3)? w : w+64;
    int tg2 = m_base + j - 3;
    float s2 = 0.f;
    if (tg2 >= 0 && tg2 < NTOK){
      const float4* p2 = (const float4*)(x + (size_t)tg2*ND + l*8);
      float4 a = p2[0], b = p2[1];
      s2 = (a.x+a.y)+(a.z+a.w)+((b.x+b.y)+(b.z+b.w));
    }
    s2 += __shfl_xor(s2,1); s2 += __shfl_xor(s2,2); s2 += __shfl_xor(s2,4);
    s2 += __shfl_xor(s2,8); s2 += __shfl_xor(s2,16); s2 += __shfl_xor(s2,32);
    if (l==0) rs_lds[j] = s2;
  }
  __syncthreads();
  {
    int rr = tid>>3, k = tid&7;
    float v = 0.f;
    if (k < NKW){
      int ti = (m_base+rr) & (NT-1);
      int idx = ti + k - 3;
      if (idx >= 0 && idx < NT) v = rs_lds[rr+k];
    }
    s_lds[rr][k] = v;
  }

  // ---- P2: gemm1 h = relu(x @ W1 + b1) -> h_lds (A-frags direct from L2-warm x)
  {
    const int wm = w>>2, wn = w&3;       // 2M x 4N waves, wave tile 32x32
    f32x4 acc1[2][2] = {};
    #pragma unroll
    for (int kc=0;kc<16;++kc){
      bf16x8 af[2], bfr[2];
      #pragma unroll
      for (int mi=0;mi<2;++mi){
        int row = wm*32 + mi*16 + (l&15);
        const float4* px = (const float4*)(x + (size_t)(m_base+row)*ND + kc*32 + (l>>4)*8);
        af[mi] = pack8(px[0], px[1]);
      }
      #pragma unroll
      for (int ni=0;ni<2;++ni){
        int n = wn*32 + ni*16 + (l&15);
        bfr[ni] = *(const bf16x8*)(W1F + ((size_t)(kc*4 + (l>>4))*128 + n)*8);
      }
      #pragma unroll
      for (int mi=0;mi<2;++mi)
        #pragma unroll
        for (int ni=0;ni<2;++ni)
          acc1[mi][ni] = __builtin_amdgcn_mfma_f32_16x16x32_bf16(af[mi], bfr[ni], acc1[mi][ni],0,0,0);
    }
    #pragma unroll
    for (int ni=0;ni<2;++ni){
      int col = wn*32 + ni*16 + (l&15);
      float bias = b1[col];
      int half = col>>6, cc = col&63;
      #pragma unroll
      for (int mi=0;mi<2;++mi)
        #pragma unroll
        for (int r=0;r<4;++r){
          int row = wm*32 + mi*16 + (l>>4)*4 + r;
          float v = fmaxf(acc1[mi][ni][r] + bias, 0.f);
          int byte = half*8192 + row*128 + ((cc*2) ^ ((row&7)<<4));
          *(u16*)((char*)h_lds + byte) = f2bf(v);
        }
    }
  }
  __syncthreads();

  // ---- P3: gemm2 A'(s*h | s) @ B3, K'=960, 15 chunks, pipelined raw barriers
  f32x4 acc[4][4] = {};
  bf16x8 bE[2][4], bO[2][4];
  const int row3 = tid>>3, slot = tid&7;

  auto loadB = [&](int c, bf16x8 (&bf)[2][4]){
    #pragma unroll
    for (int kk=0;kk<2;++kk)
      #pragma unroll
      for (int ni=0;ni<4;++ni){
        int rowB = w*64 + ni*16 + (l&15);
        bf[kk][ni] = *(const bf16x8*)(B3 + ((size_t)((c*2+kk)*4 + (l>>4))*512 + rowB)*8);
      }
  };
  auto stageA = [&](u16* dst, int c){
    u16 u[8];
    if (c < 14){
      float sv = s_lds[row3][c>>1];
      const char* src = (const char*)h_lds + (c&1)*8192 + row3*128 + ((slot*16) ^ ((row3&7)<<4));
      u16x8 hv = *(const u16x8*)src;
      #pragma unroll
      for (int j=0;j<8;++j) u[j] = f2bf(bf2f(hv[j])*sv);
    } else {
      #pragma unroll
      for (int j=0;j<8;++j){
        int e2 = slot*8+j;
        u[j] = (e2<NKW)? f2bf(s_lds[row3][e2]) : (u16)0;
      }
    }
    store16((char*)dst + row3*128 + ((slot*16) ^ ((row3&7)<<4)), u);
  };
  auto mfmaC = [&](const u16* A, bf16x8 (&b)[2][4]){
    __builtin_amdgcn_s_setprio(1);
    #pragma unroll
    for (int kk=0;kk<2;++kk){
      bf16x8 af[4];
      #pragma unroll
      for (int mi=0;mi<4;++mi){
        int r2 = mi*16 + (l&15);
        int byte = r2*128 + (((kk*64)+((l>>4)*16)) ^ ((r2&7)<<4));
        af[mi] = *(const bf16x8*)((const char*)A + byte);
      }
      #pragma unroll
      for (int mi=0;mi<4;++mi)
        #pragma unroll
        for (int ni=0;ni<4;++ni)
          acc[mi][ni] = __builtin_amdgcn_mfma_f32_16x16x32_bf16(af[mi], b[kk][ni], acc[mi][ni],0,0,0);
    }
    __builtin_amdgcn_s_setprio(0);
  };
  #define SYNC() do{ __builtin_amdgcn_sched_barrier(0); \
      asm volatile("s_waitcnt lgkmcnt(0)" ::: "memory"); \
      __builtin_amdgcn_s_barrier(); \
      __builtin_amdgcn_sched_barrier(0); }while(0)

  loadB(0, bE);
  stageA(At0, 0);
  SYNC();
  #pragma unroll
  for (int t=0;t<7;++t){
    loadB(2*t+1, bO);
    stageA(At1, 2*t+1);
    mfmaC(At0, bE);
    SYNC();
    loadB(2*t+2, bE);
    stageA(At0, 2*t+2);
    mfmaC(At1, bO);
    SYNC();
  }
  mfmaC(At0, bE);
  #undef SYNC

  // ---- P4: residual + LN + relu
  #pragma unroll
  for (int mi=0;mi<4;++mi){
    #pragma unroll
    for (int r=0;r<4;++r){
      int m = mi*16 + (l>>4)*4 + r;
      int tg = m_base + m;
      float ps=0.f, pq=0.f;
      #pragma unroll
      for (int ni=0;ni<4;++ni){
        int n = w*64 + ni*16 + (l&15);
        float v = acc[mi][ni][r] + x[(size_t)tg*ND + n];
        acc[mi][ni][r] = v;
        ps += v; pq += v*v;
      }
      #pragma unroll
      for (int msk=1; msk<16; msk<<=1){ ps += __shfl_xor(ps,msk); pq += __shfl_xor(pq,msk); }
      if ((l&15)==0){ red_s[m][w]=ps; red_q[m][w]=pq; }
    }
  }
  __syncthreads();
  if (tid < 64){
    float ssum=0.f, sq=0.f;
    #pragma unroll
    for (int ww=0; ww<8; ++ww){ ssum += red_s[tid][ww]; sq += red_q[tid][ww]; }
    float mu = ssum * (1.0f/ND);
    float var = sq*(1.0f/ND) - mu*mu;
    mu_lds[tid] = mu;
    rstd_lds[tid] = rsqrtf(var + 1e-3f);
  }
  __syncthreads();
  float gv[4], bv[4];
  #pragma unroll
  for (int ni=0;ni<4;++ni){
    int n = w*64 + ni*16 + (l&15);
    gv[ni] = gamma[n]; bv[ni] = beta[n];
  }
  #pragma unroll
  for (int mi=0;mi<4;++mi){
    #pragma unroll
    for (int r=0;r<4;++r){
      int m = mi*16 + (l>>4)*4 + r;
      int tg = m_base + m;
      float mu = mu_lds[m], rstd = rstd_lds[m];
      #pragma unroll
      for (int ni=0;ni<4;++ni){
        int n = w*64 + ni*16 + (l&15);
        float v = (acc[mi][ni][r]-mu)*rstd*gv[ni] + bv[ni];
        out[(size_t)tg*ND + n] = fmaxf(v, 0.f);
      }
    }
  }
}

extern "C" void kernel_launch(void* const* d_in, const int* in_sizes, int n_in,
                              void* d_out, int out_size, void* d_ws, size_t ws_size,
                              hipStream_t stream)
{
  (void)in_sizes; (void)n_in; (void)out_size; (void)ws_size;
  const float* x     = (const float*)d_in[0];
  const float* W1    = (const float*)d_in[1];
  const float* b1    = (const float*)d_in[2];
  const float* W2    = (const float*)d_in[3];
  const float* b2    = (const float*)d_in[4];
  const float* gamma = (const float*)d_in[5];
  const float* beta  = (const float*)d_in[6];
  float* out = (float*)d_out;

  char* ws = (char*)d_ws;
  u16* W1F = (u16*)(ws);               // 131072 B
  u16* B3  = (u16*)(ws + 131072);      // 983040 B

  prep2_kernel<<<272, 256, 0, stream>>>(W1, W2, b2, W1F, B3);
  fused_kernel<<<256, 512, 0, stream>>>(x, W1F, b1, B3, gamma, beta, out);
}